// Round 1
// baseline (314.362 us; speedup 1.0000x reference)
//
#include <hip/hip_runtime.h>
#include <math.h>

#define CH 16

__device__ __forceinline__ float rcp_fast(float x) { return __builtin_amdgcn_rcpf(x); }

// tanh(x) = 1 - 2/(1+exp(2x)); saturates correctly (exp->inf => 1, exp->0 => -1)
__device__ __forceinline__ float tanh_fast(float x) {
    float t = __expf(2.0f * x);
    return fmaf(-2.0f, rcp_fast(1.0f + t), 1.0f);
}

__device__ __forceinline__ float sigmoid_fast(float x) {
    return rcp_fast(1.0f + __expf(-x));
}

__device__ __forceinline__ float softplus_precise(float x) {
    // one-time per thread; x ~ -1.5 here, plain form is plenty accurate
    return logf(1.0f + expf(x));
}

__global__ __launch_bounds__(256) void eb_kernel(
    const float* __restrict__ inp, const float* __restrict__ nz,
    const float* __restrict__ m0, const float* __restrict__ b0, const float* __restrict__ f0,
    const float* __restrict__ m1, const float* __restrict__ b1, const float* __restrict__ f1,
    const float* __restrict__ m2, const float* __restrict__ b2, const float* __restrict__ f2,
    const float* __restrict__ m3, const float* __restrict__ b3, const float* __restrict__ f3,
    float* __restrict__ out, int total)
{
    const int tid = blockIdx.x * blockDim.x + threadIdx.x;
    const int c = tid & (CH - 1);   // stride is a multiple of 16 -> fixed channel per thread

    // ---- load + transform weights for this thread's channel (once) ----
    float sp0[3], bb0[3], tt0[3];
    float sp1[9], bb1[3], tt1[3];
    float sp2[9], bb2[3], tt2[3];
    float sp3[3], bb3, tt3;

#pragma unroll
    for (int j = 0; j < 3; j++) {
        sp0[j] = softplus_precise(m0[c * 3 + j]);
        bb0[j] = b0[c * 3 + j];
        tt0[j] = tanhf(f0[c * 3 + j]);
        bb1[j] = b1[c * 3 + j];
        tt1[j] = tanhf(f1[c * 3 + j]);
        bb2[j] = b2[c * 3 + j];
        tt2[j] = tanhf(f2[c * 3 + j]);
        sp3[j] = softplus_precise(m3[c * 3 + j]);
    }
#pragma unroll
    for (int j = 0; j < 9; j++) {
        sp1[j] = softplus_precise(m1[c * 9 + j]);
        sp2[j] = softplus_precise(m2[c * 9 + j]);
    }
    bb3 = b3[c];
    tt3 = tanhf(f3[c]);

    // ---- per-x 4-layer MLP, fully in registers ----
    auto run_net = [&](float x) -> float {
        float v0, v1, v2;
        {
            float l0 = fmaf(sp0[0], x, bb0[0]); v0 = fmaf(tt0[0], tanh_fast(l0), l0);
            float l1 = fmaf(sp0[1], x, bb0[1]); v1 = fmaf(tt0[1], tanh_fast(l1), l1);
            float l2 = fmaf(sp0[2], x, bb0[2]); v2 = fmaf(tt0[2], tanh_fast(l2), l2);
        }
        float w0, w1, w2;
        {
            float l0 = fmaf(sp1[0], v0, fmaf(sp1[1], v1, fmaf(sp1[2], v2, bb1[0])));
            float l1 = fmaf(sp1[3], v0, fmaf(sp1[4], v1, fmaf(sp1[5], v2, bb1[1])));
            float l2 = fmaf(sp1[6], v0, fmaf(sp1[7], v1, fmaf(sp1[8], v2, bb1[2])));
            w0 = fmaf(tt1[0], tanh_fast(l0), l0);
            w1 = fmaf(tt1[1], tanh_fast(l1), l1);
            w2 = fmaf(tt1[2], tanh_fast(l2), l2);
        }
        {
            float l0 = fmaf(sp2[0], w0, fmaf(sp2[1], w1, fmaf(sp2[2], w2, bb2[0])));
            float l1 = fmaf(sp2[3], w0, fmaf(sp2[4], w1, fmaf(sp2[5], w2, bb2[1])));
            float l2 = fmaf(sp2[6], w0, fmaf(sp2[7], w1, fmaf(sp2[8], w2, bb2[2])));
            v0 = fmaf(tt2[0], tanh_fast(l0), l0);
            v1 = fmaf(tt2[1], tanh_fast(l1), l1);
            v2 = fmaf(tt2[2], tanh_fast(l2), l2);
        }
        float l = fmaf(sp3[0], v0, fmaf(sp3[1], v1, fmaf(sp3[2], v2, bb3)));
        return fmaf(tt3, tanh_fast(l), l);
    };

    const int stride = gridDim.x * blockDim.x;
    for (int e = tid; e < total; e += stride) {
        float o = inp[e] + nz[e] - 0.5f;
        float lo = run_net(o - 0.5f);
        float up = run_net(o + 0.5f);
        out[e] = o;

        float sum = lo + up;
        float s = (sum > 0.0f) ? -1.0f : ((sum < 0.0f) ? 1.0f : 0.0f);
        float a = sigmoid_fast(s * up);
        float b = sigmoid_fast(s * lo);
        float lik = fabsf(a - b);
        out[total + e] = fmaxf(lik, 1e-9f);
    }
}

extern "C" void kernel_launch(void* const* d_in, const int* in_sizes, int n_in,
                              void* d_out, int out_size, void* d_ws, size_t ws_size,
                              hipStream_t stream) {
    const float* inp = (const float*)d_in[0];
    const float* nz  = (const float*)d_in[1];
    const float* m0 = (const float*)d_in[2];
    const float* b0 = (const float*)d_in[3];
    const float* f0 = (const float*)d_in[4];
    const float* m1 = (const float*)d_in[5];
    const float* b1 = (const float*)d_in[6];
    const float* f1 = (const float*)d_in[7];
    const float* m2 = (const float*)d_in[8];
    const float* b2 = (const float*)d_in[9];
    const float* f2 = (const float*)d_in[10];
    const float* m3 = (const float*)d_in[11];
    const float* b3 = (const float*)d_in[12];
    const float* f3 = (const float*)d_in[13];
    float* out = (float*)d_out;

    const int total = in_sizes[0];          // N*C = 16777216
    const int threads = 256;
    const int blocks = 2048;                // stride = 524288, multiple of 16

    hipLaunchKernelGGL(eb_kernel, dim3(blocks), dim3(threads), 0, stream,
                       inp, nz, m0, b0, f0, m1, b1, f1, m2, b2, f2, m3, b3, f3,
                       out, total);
}

// Round 3
// 270.094 us; speedup vs baseline: 1.1639x; 1.1639x over previous
//
#include <hip/hip_runtime.h>
#include <math.h>

#define CH 16
#define NINT 256                 // intervals
#define NPTS (NINT + 1)          // 257 samples per channel
#define TAB_ELEMS (CH * NPTS)    // 4112 floats
#define ORIGIN 8.0f              // table covers o in [-8, 8]
#define INV_H 16.0f              // 1/h, h = 16/256

// ---------------- setup kernel: build per-channel likelihood table ----------------

__device__ __forceinline__ float softplus_ref(float x) { return log1pf(expf(x)); }

__device__ float eval_net_exact(float x,
                                const float* sp0, const float* bb0, const float* tt0,
                                const float* sp1, const float* bb1, const float* tt1,
                                const float* sp2, const float* bb2, const float* tt2,
                                const float* sp3, float bb3, float tt3)
{
    float v0, v1, v2;
    {
        float l0 = fmaf(sp0[0], x, bb0[0]); v0 = fmaf(tt0[0], tanhf(l0), l0);
        float l1 = fmaf(sp0[1], x, bb0[1]); v1 = fmaf(tt0[1], tanhf(l1), l1);
        float l2 = fmaf(sp0[2], x, bb0[2]); v2 = fmaf(tt0[2], tanhf(l2), l2);
    }
    float w0, w1, w2;
    {
        float l0 = fmaf(sp1[0], v0, fmaf(sp1[1], v1, fmaf(sp1[2], v2, bb1[0])));
        float l1 = fmaf(sp1[3], v0, fmaf(sp1[4], v1, fmaf(sp1[5], v2, bb1[1])));
        float l2 = fmaf(sp1[6], v0, fmaf(sp1[7], v1, fmaf(sp1[8], v2, bb1[2])));
        w0 = fmaf(tt1[0], tanhf(l0), l0);
        w1 = fmaf(tt1[1], tanhf(l1), l1);
        w2 = fmaf(tt1[2], tanhf(l2), l2);
    }
    {
        float l0 = fmaf(sp2[0], w0, fmaf(sp2[1], w1, fmaf(sp2[2], w2, bb2[0])));
        float l1 = fmaf(sp2[3], w0, fmaf(sp2[4], w1, fmaf(sp2[5], w2, bb2[1])));
        float l2 = fmaf(sp2[6], w0, fmaf(sp2[7], w1, fmaf(sp2[8], w2, bb2[2])));
        v0 = fmaf(tt2[0], tanhf(l0), l0);
        v1 = fmaf(tt2[1], tanhf(l1), l1);
        v2 = fmaf(tt2[2], tanhf(l2), l2);
    }
    float l = fmaf(sp3[0], v0, fmaf(sp3[1], v1, fmaf(sp3[2], v2, bb3)));
    return fmaf(tt3, tanhf(l), l);
}

__global__ __launch_bounds__(256) void eb_table_kernel(
    const float* __restrict__ m0, const float* __restrict__ b0, const float* __restrict__ f0,
    const float* __restrict__ m1, const float* __restrict__ b1, const float* __restrict__ f1,
    const float* __restrict__ m2, const float* __restrict__ b2, const float* __restrict__ f2,
    const float* __restrict__ m3, const float* __restrict__ b3, const float* __restrict__ f3,
    float* __restrict__ tab)
{
    int t = blockIdx.x * blockDim.x + threadIdx.x;
    if (t >= TAB_ELEMS) return;
    int c = t / NPTS;
    int k = t - c * NPTS;

    float sp0[3], bb0[3], tt0[3];
    float sp1[9], bb1[3], tt1[3];
    float sp2[9], bb2[3], tt2[3];
    float sp3[3];
#pragma unroll
    for (int j = 0; j < 3; j++) {
        sp0[j] = softplus_ref(m0[c * 3 + j]);
        bb0[j] = b0[c * 3 + j];
        tt0[j] = tanhf(f0[c * 3 + j]);
        bb1[j] = b1[c * 3 + j];
        tt1[j] = tanhf(f1[c * 3 + j]);
        bb2[j] = b2[c * 3 + j];
        tt2[j] = tanhf(f2[c * 3 + j]);
        sp3[j] = softplus_ref(m3[c * 3 + j]);
    }
#pragma unroll
    for (int j = 0; j < 9; j++) {
        sp1[j] = softplus_ref(m1[c * 9 + j]);
        sp2[j] = softplus_ref(m2[c * 9 + j]);
    }
    float bb3 = b3[c];
    float tt3 = tanhf(f3[c]);

    float o = -ORIGIN + (float)k * (1.0f / INV_H);
    float lo = eval_net_exact(o - 0.5f, sp0, bb0, tt0, sp1, bb1, tt1, sp2, bb2, tt2, sp3, bb3, tt3);
    float up = eval_net_exact(o + 0.5f, sp0, bb0, tt0, sp1, bb1, tt1, sp2, bb2, tt2, sp3, bb3, tt3);

    float sum = lo + up;
    float s = (sum > 0.0f) ? -1.0f : ((sum < 0.0f) ? 1.0f : 0.0f);
    float su = 1.0f / (1.0f + expf(-s * up));
    float sl = 1.0f / (1.0f + expf(-s * lo));
    tab[t] = fmaxf(fabsf(su - sl), 1e-9f);
}

// ---------------- main kernel: stream + LDS table lerp ----------------

__global__ __launch_bounds__(256) void eb_main_kernel(
    const float4* __restrict__ inp, const float4* __restrict__ nz,
    const float* __restrict__ tab, float4* __restrict__ out, int nvec)
{
    __shared__ float lds[TAB_ELEMS];
    for (int j = threadIdx.x; j < TAB_ELEMS; j += 256) lds[j] = tab[j];
    __syncthreads();

    const int gtid = blockIdx.x * 256 + threadIdx.x;
    const int stride = gridDim.x * 256;

    for (int v = gtid; v < nvec; v += stride) {
        float4 a = inp[v];
        float4 b = nz[v];
        const int c0 = (v & 3) * 4;   // element channel = (4v + j) & 15

        float4 o, lik;

        {
            float oe = a.x + b.x - 0.5f;
            float t = fminf(fmaxf(fmaf(oe, INV_H, ORIGIN * INV_H), 0.0f), 255.999f);
            int i = (int)t;
            float fr = t - (float)i;
            const float* p = &lds[(c0 + 0) * NPTS + i];
            float v0 = p[0], v1 = p[1];
            o.x = oe; lik.x = fmaxf(fmaf(fr, v1 - v0, v0), 1e-9f);
        }
        {
            float oe = a.y + b.y - 0.5f;
            float t = fminf(fmaxf(fmaf(oe, INV_H, ORIGIN * INV_H), 0.0f), 255.999f);
            int i = (int)t;
            float fr = t - (float)i;
            const float* p = &lds[(c0 + 1) * NPTS + i];
            float v0 = p[0], v1 = p[1];
            o.y = oe; lik.y = fmaxf(fmaf(fr, v1 - v0, v0), 1e-9f);
        }
        {
            float oe = a.z + b.z - 0.5f;
            float t = fminf(fmaxf(fmaf(oe, INV_H, ORIGIN * INV_H), 0.0f), 255.999f);
            int i = (int)t;
            float fr = t - (float)i;
            const float* p = &lds[(c0 + 2) * NPTS + i];
            float v0 = p[0], v1 = p[1];
            o.z = oe; lik.z = fmaxf(fmaf(fr, v1 - v0, v0), 1e-9f);
        }
        {
            float oe = a.w + b.w - 0.5f;
            float t = fminf(fmaxf(fmaf(oe, INV_H, ORIGIN * INV_H), 0.0f), 255.999f);
            int i = (int)t;
            float fr = t - (float)i;
            const float* p = &lds[(c0 + 3) * NPTS + i];
            float v0 = p[0], v1 = p[1];
            o.w = oe; lik.w = fmaxf(fmaf(fr, v1 - v0, v0), 1e-9f);
        }

        out[v] = o;
        out[nvec + v] = lik;
    }
}

// ---------------- launcher ----------------

extern "C" void kernel_launch(void* const* d_in, const int* in_sizes, int n_in,
                              void* d_out, int out_size, void* d_ws, size_t ws_size,
                              hipStream_t stream) {
    const float* inp = (const float*)d_in[0];
    const float* nz  = (const float*)d_in[1];
    const float* m0 = (const float*)d_in[2];
    const float* b0 = (const float*)d_in[3];
    const float* f0 = (const float*)d_in[4];
    const float* m1 = (const float*)d_in[5];
    const float* b1 = (const float*)d_in[6];
    const float* f1 = (const float*)d_in[7];
    const float* m2 = (const float*)d_in[8];
    const float* b2 = (const float*)d_in[9];
    const float* f2 = (const float*)d_in[10];
    const float* m3 = (const float*)d_in[11];
    const float* b3 = (const float*)d_in[12];
    const float* f3 = (const float*)d_in[13];

    float* tab = (float*)d_ws;               // 16*257 floats = 16448 B
    const int total = in_sizes[0];           // 16777216
    const int nvec = total >> 2;

    hipLaunchKernelGGL(eb_table_kernel, dim3((TAB_ELEMS + 255) / 256), dim3(256), 0, stream,
                       m0, b0, f0, m1, b1, f1, m2, b2, f2, m3, b3, f3, tab);

    hipLaunchKernelGGL(eb_main_kernel, dim3(2048), dim3(256), 0, stream,
                       (const float4*)inp, (const float4*)nz, tab, (float4*)d_out, nvec);
}